// Round 1
// baseline (89.841 us; speedup 1.0000x reference)
//
#include <hip/hip_runtime.h>

// Closed form of the reference:
//   out = D + 0.5 * sum_k [ e^{-pi*(y[k+1]-y[k])^2} + e^{-pi*(d[k+1]-d[k])^2}
//                         - e^{-pi*(d[k+1]-y[k+1])^2} - e^{-pi*(d[k+1]-y[k])^2}
//                         - e^{-pi*(d[k]-y[k+1])^2}   - e^{-pi*(d[k]-y[k])^2} ]
// with D = N-2, k in [0, D).  (log_sqrt_pi == 0 exactly since SIG = 1/sqrt(2pi).)

#define PI_F 3.14159265358979323846f

__global__ __launch_bounds__(256) void casamento_kernel(
    const float* __restrict__ d, const float* __restrict__ y,
    float* __restrict__ out, int D)
{
    int tid = blockIdx.x * blockDim.x + threadIdx.x;
    int stride = gridDim.x * blockDim.x;

    float acc = 0.0f;
    for (int k = tid; k < D; k += stride) {
        float d0 = d[k], d1 = d[k + 1];
        float y0 = y[k], y1 = y[k + 1];

        float dy = y1 - y0;
        float dd = d1 - d0;
        float c00 = d1 - y1;
        float c01 = d1 - y0;
        float c10 = d0 - y1;
        float c11 = d0 - y0;

        float t = __expf(-PI_F * dy * dy) + __expf(-PI_F * dd * dd)
                - __expf(-PI_F * c00 * c00) - __expf(-PI_F * c01 * c01)
                - __expf(-PI_F * c10 * c10) - __expf(-PI_F * c11 * c11);
        acc += 0.5f * t;
    }

    // wave-64 butterfly reduce
    for (int off = 32; off > 0; off >>= 1)
        acc += __shfl_down(acc, off, 64);

    __shared__ float warp_sums[4];  // 256 threads / 64 lanes
    int lane = threadIdx.x & 63;
    int wid  = threadIdx.x >> 6;
    if (lane == 0) warp_sums[wid] = acc;
    __syncthreads();

    if (threadIdx.x == 0) {
        float s = warp_sums[0] + warp_sums[1] + warp_sums[2] + warp_sums[3];
        if (blockIdx.x == 0) s += (float)D;  // the 4D/4 constant term
        atomicAdd(out, s);
    }
}

extern "C" void kernel_launch(void* const* d_in, const int* in_sizes, int n_in,
                              void* d_out, int out_size, void* d_ws, size_t ws_size,
                              hipStream_t stream) {
    const float* d = (const float*)d_in[0];
    const float* y = (const float*)d_in[1];
    float* out = (float*)d_out;

    int N = in_sizes[0];
    int D = N - 2;

    // d_out is poisoned 0xAA before every timed launch — zero it (async, capture-safe).
    hipMemsetAsync(out, 0, sizeof(float), stream);

    const int block = 256;
    const int grid = 1024;  // 4 blocks/CU, grid-stride over 4M elements
    casamento_kernel<<<grid, block, 0, stream>>>(d, y, out, D);
}